// Round 16
// baseline (298.030 us; speedup 1.0000x reference)
//
#include <hip/hip_runtime.h>
#include <hip/hip_bf16.h>

typedef __attribute__((ext_vector_type(4)))  float f32x4;
typedef __attribute__((ext_vector_type(16))) float f32x16;
typedef __attribute__((ext_vector_type(8)))  short short8;

#define XROWS 8195                     // 3 guard rows + 8192
#define KCSTRIDE (XROWS * 16)          // 131120 elems per kc-slab per batch
#define XFB (64 * KCSTRIDE)            // 8,391,680 elems per batch

__device__ __forceinline__ short f2bf(float f) {
    union { __hip_bfloat16 h; short s; } u;
    u.h = __float2bfloat16(f);
    return u.s;
}

__device__ __forceinline__ void async16(const void* g, void* l) {
    __builtin_amdgcn_global_load_lds(
        (const __attribute__((address_space(1))) unsigned int*)g,
        (__attribute__((address_space(3))) unsigned int*)l, 16, 0, 0);
}

// ---------------------------------------------------------------------------
// Prepass 1: x fp32 [4][8192][1024] -> Xf bf16 fragment-major:
//   Xf[batch][kc(64)][row(8195)][16], Xf[b][kc][3+s][e] = x[b][s][kc*16+e],
//   rows 0..2 per (b,kc) are zero guards. LDS-tiled 64row x 256col transpose.
// ---------------------------------------------------------------------------
__global__ void x_to_frag(const float* __restrict__ x,
                          __hip_bfloat16* __restrict__ Xf) {
    if (blockIdx.x == 2048) {   // zero the 4*64*3 guard chunk-rows
        int t0 = threadIdx.x;
#pragma unroll
        for (int k = 0; k < 3; k++) {
            int id = t0 + k * 256;            // 0..767
            int b  = id / 192;
            int rem = id % 192;
            int kc = rem / 3, r = rem % 3;
            size_t o = (size_t)b * XFB + (size_t)kc * KCSTRIDE + r * 16;
            *reinterpret_cast<short8*>(&Xf[o])     = (short8){0,0,0,0,0,0,0,0};
            *reinterpret_cast<short8*>(&Xf[o + 8]) = (short8){0,0,0,0,0,0,0,0};
        }
        return;
    }
    __shared__ __hip_bfloat16 tile[64][264];
    int blk   = blockIdx.x;        // 0..2047
    int bt    = blk >> 9;          // batch (512 blocks/batch)
    int rtile = (blk >> 2) & 127;
    int ktile = blk & 3;
    int r0 = rtile * 64;
    int c0 = ktile * 256;
    int t  = threadIdx.x;
    {   // read: thread covers row r, 64 cols
        int r = t >> 2, q = t & 3;
        const float* src = x + ((size_t)((bt << 13) + r0 + r) << 10) + c0 + q * 64;
#pragma unroll
        for (int j = 0; j < 8; j++) {
            f32x4 lo = *reinterpret_cast<const f32x4*>(src + j * 8);
            f32x4 hi = *reinterpret_cast<const f32x4*>(src + j * 8 + 4);
            short8 pk;
            pk[0] = f2bf(lo[0]); pk[1] = f2bf(lo[1]); pk[2] = f2bf(lo[2]); pk[3] = f2bf(lo[3]);
            pk[4] = f2bf(hi[0]); pk[5] = f2bf(hi[1]); pk[6] = f2bf(hi[2]); pk[7] = f2bf(hi[3]);
            *reinterpret_cast<short8*>(&tile[r][q * 64 + j * 8]) = pk;
        }
    }
    __syncthreads();
    {   // write: thread (kcl = t>>4, rl = t&15) stores rows rl + i*16
        int kcl = t >> 4, rl = t & 15;
        int kc  = ktile * 16 + kcl;
        size_t base = (size_t)bt * XFB + (size_t)kc * KCSTRIDE +
                      (size_t)(3 + r0) * 16;
#pragma unroll
        for (int i = 0; i < 4; i++) {
            int row = rl + i * 16;
            short8 a = *reinterpret_cast<const short8*>(&tile[row][kcl * 16]);
            short8 b = *reinterpret_cast<const short8*>(&tile[row][kcl * 16 + 8]);
            *reinterpret_cast<short8*>(&Xf[base + (size_t)row * 16])     = a;
            *reinterpret_cast<short8*>(&Xf[base + (size_t)row * 16 + 8]) = b;
        }
    }
}

// ---------------------------------------------------------------------------
// Prepass 2: kernels [4096][1024] fp32 -> Kf bf16 fragment-major:
//   Kf[kc(256)][f(1024)][16], Kf[kc][f][e] = kern[kc*16+e][f].
// ---------------------------------------------------------------------------
__global__ void kconv_frag2(const float* __restrict__ kern,
                            __hip_bfloat16* __restrict__ Kf) {
    __shared__ float tile[16][260];
    int kc = blockIdx.x >> 2;      // 0..255
    int f0 = (blockIdx.x & 3) << 8;
    int t  = threadIdx.x;
    {   // read 16 k-rows x 256 f, coalesced
        int r = t >> 4, seg = t & 15;
        const float* src = kern + (size_t)(kc * 16 + r) * 1024 + f0 + seg * 16;
#pragma unroll
        for (int j = 0; j < 4; j++) {
            f32x4 v = *reinterpret_cast<const f32x4*>(src + j * 4);
            tile[r][seg * 16 + j * 4 + 0] = v[0];
            tile[r][seg * 16 + j * 4 + 1] = v[1];
            tile[r][seg * 16 + j * 4 + 2] = v[2];
            tile[r][seg * 16 + j * 4 + 3] = v[3];
        }
    }
    __syncthreads();
    {   // write: thread t = f-local, gather column e=0..15
        short8 a, b;
#pragma unroll
        for (int e = 0; e < 8; e++)  a[e] = f2bf(tile[e][t]);
#pragma unroll
        for (int e = 0; e < 8; e++)  b[e] = f2bf(tile[e + 8][t]);
        size_t base = (size_t)kc * 16384 + (size_t)(f0 + t) * 16;
        *reinterpret_cast<short8*>(&Kf[base])     = a;
        *reinterpret_cast<short8*>(&Kf[base + 8]) = b;
    }
}

// ---------------------------------------------------------------------------
// Main GEMM — fragment-major LDS both operands, one barrier per K-tile,
//   MFMA 32x32x16 (R11-verified maps + epilogue):
//   BM=BN=256, 8 waves (2M x 4N), wave tile 128x64.
//   LDS 128 KiB = 2-tile dbuf x (A [ks(4)][row(256)][16] + B same).
//   STAGE: 8 async16, source contiguous 1KB (fragment-major global),
//   dest linear (identity "swizzle" - rule 21 trivially satisfied).
//   Reads: base + l31*32B + lh*16B = contiguous 1KB per instruction -
//   canonical conflict-free (R8-measured 0 conflicts). No XOR anywhere.
//   Per tile: vmcnt(0) [issued ~3/4 tile ago - free] + 1 barrier; 4
//   ks-chunks {6 ds_read_b128 -> 8 MFMA}; stage T+1 after ks0 reads.
// ---------------------------------------------------------------------------
__global__ void __launch_bounds__(512, 2)
altconv_gemm14(const __hip_bfloat16* __restrict__ Xf,   // fragment-major x
               const __hip_bfloat16* __restrict__ Kf,   // fragment-major K
               const float* __restrict__ biases,        // [4][1024]
               float* __restrict__ out) {               // [32768][1024]
    __shared__ alignas(16) __hip_bfloat16 LS[65536];    // 128 KiB

    // bijective XCD swizzle (512 % 8 == 0); nt fastest within an XCD chunk
    int bid  = blockIdx.x;
    int tid2 = (bid & 7) * 64 + (bid >> 3);
    int mt = tid2 >> 2;           // 0..127
    int nt = tid2 & 3;            // 0..3
    int bm0   = mt << 8;
    int batch = bm0 >> 13;
    int srow0 = bm0 & 8191;
    int bn0   = nt << 8;
    const __hip_bfloat16* xfb = Xf + (size_t)batch * XFB;

    int t    = threadIdx.x;
    int lane = t & 63;
    int wid  = t >> 6;            // 0..7
    int wr = wid >> 2, wc = wid & 3;
    int l31 = lane & 31, lh = lane >> 5;

    // staging: thread covers row wid*32 + (lane>>1), half (lane&1)
    int sThr = (wid * 32 + (lane >> 1)) * 16 + (lane & 1) * 8;  // src elem off
    int dThr = wid * 512 + lane * 8;                            // LDS dest off

    // fragment read offsets (within a ks-slab of 4096 elems)
    int aOff[4], bOff[2];
#pragma unroll
    for (int mb = 0; mb < 4; mb++)
        aOff[mb] = (wr * 128 + mb * 32 + l31) * 16 + lh * 8;
#pragma unroll
    for (int nb = 0; nb < 2; nb++)
        bOff[nb] = 16384 + (wc * 64 + nb * 32 + l31) * 16 + lh * 8;

    f32x16 acc[4][2];
#pragma unroll
    for (int mb = 0; mb < 4; mb++)
#pragma unroll
        for (int nb = 0; nb < 2; nb++)
#pragma unroll
            for (int r = 0; r < 16; r++) acc[mb][nb][r] = 0.f;

#define STAGET(T) do {                                                        \
        int tap_ = (T) >> 4;                                                  \
        int c0k_ = ((T) & 15) << 2;                                           \
        int g0_  = srow0 + 3 - tap_;                                          \
        const __hip_bfloat16* aS_ = xfb + (size_t)g0_ * 16 + sThr;            \
        const __hip_bfloat16* bS_ = Kf + (size_t)bn0 * 16 + sThr;             \
        int dE_ = ((T) & 1) << 15;                                            \
        _Pragma("unroll")                                                     \
        for (int ks = 0; ks < 4; ks++)                                        \
            async16(aS_ + (size_t)(c0k_ + ks) * KCSTRIDE,                     \
                    &LS[dE_ + ks * 4096 + dThr]);                             \
        _Pragma("unroll")                                                     \
        for (int ks = 0; ks < 4; ks++)                                        \
            async16(bS_ + (size_t)((T) * 4 + ks) * 16384,                     \
                    &LS[dE_ + 16384 + ks * 4096 + dThr]);                     \
    } while (0)

    // prologue: stage tile 0
    STAGET(0);

    for (int T = 0; T < 64; T++) {
        asm volatile("s_waitcnt vmcnt(0)" ::: "memory");   // T landed (aged)
        __builtin_amdgcn_s_barrier();
        asm volatile("" ::: "memory");
        int base = (T & 1) << 15;
        bool dostage = (T < 63);
#pragma unroll
        for (int ks = 0; ks < 4; ks++) {
            short8 af[4], bf2[2];
#pragma unroll
            for (int mb = 0; mb < 4; mb++)
                af[mb] = *reinterpret_cast<const short8*>(
                    &LS[base + ks * 4096 + aOff[mb]]);
#pragma unroll
            for (int nb = 0; nb < 2; nb++)
                bf2[nb] = *reinterpret_cast<const short8*>(
                    &LS[base + ks * 4096 + bOff[nb]]);
            if (ks == 0 && dostage) STAGET(T + 1);
#pragma unroll
            for (int mb = 0; mb < 4; mb++)
#pragma unroll
                for (int nb = 0; nb < 2; nb++)
                    acc[mb][nb] = __builtin_amdgcn_mfma_f32_32x32x16_bf16(
                        af[mb], bf2[nb], acc[mb][nb], 0, 0, 0);
        }
    }

    // epilogue (R11/R12-verified): col=lane&31, row=(r&3)+8*(r>>2)+4*lh
#pragma unroll
    for (int nb = 0; nb < 2; nb++) {
        int gc = bn0 + wc * 64 + nb * 32 + l31;
        float bsum = biases[gc] + biases[1024 + gc] + biases[2048 + gc] + biases[3072 + gc];
#pragma unroll
        for (int mb = 0; mb < 4; mb++) {
            int rowb = bm0 + wr * 128 + mb * 32 + 4 * lh;
#pragma unroll
            for (int r = 0; r < 16; r++) {
                int row = rowb + (r & 3) + 8 * (r >> 2);
                out[(size_t)row * 1024 + gc] = acc[mb][nb][r] + bsum;
            }
        }
    }
#undef STAGET
}

// ---------------------------------------------------------------------------
// Fallback: plain fp32 (no workspace needed), correct but slow
// ---------------------------------------------------------------------------
__global__ void fallback_conv(const float* __restrict__ x, const float* __restrict__ kern,
                              const float* __restrict__ biases, float* __restrict__ out) {
    __shared__ float xs[1024];
    int row = blockIdx.x;
    int f = (blockIdx.y << 8) + threadIdx.x;
    int batch = row >> 13, s = row & 8191;
    const float* xb = x + (((size_t)batch << 13) << 10);
    float acc = 0.f;
    for (int tap = 0; tap < 4; tap++) {
        int ss = s - tap;
        __syncthreads();
        for (int i = threadIdx.x; i < 1024; i += 256)
            xs[i] = (ss >= 0) ? xb[((size_t)ss << 10) + i] : 0.f;
        __syncthreads();
        const float* kp = kern + ((size_t)tap << 20) + f;
        float a = 0.f;
        for (int d = 0; d < 1024; d++) a += xs[d] * kp[(size_t)d << 10];
        acc += a + biases[(tap << 10) + f];
    }
    out[((size_t)row << 10) + f] = acc;
}

extern "C" void kernel_launch(void* const* d_in, const int* in_sizes, int n_in,
                              void* d_out, int out_size, void* d_ws, size_t ws_size,
                              hipStream_t stream) {
    const float* x      = (const float*)d_in[0];
    const float* kern   = (const float*)d_in[1];
    const float* biases = (const float*)d_in[2];
    float* out = (float*)d_out;

    const size_t xf_bytes = (size_t)4 * XFB * sizeof(__hip_bfloat16);       // 67.1 MB
    const size_t kf_bytes = (size_t)4096 * 1024 * sizeof(__hip_bfloat16);   // 8.4 MB

    if (ws_size >= xf_bytes + kf_bytes) {
        __hip_bfloat16* Xf = (__hip_bfloat16*)d_ws;
        __hip_bfloat16* Kf = (__hip_bfloat16*)((char*)d_ws + xf_bytes);
        x_to_frag<<<2049, 256, 0, stream>>>(x, Xf);
        kconv_frag2<<<1024, 256, 0, stream>>>(kern, Kf);
        altconv_gemm14<<<512, 512, 0, stream>>>(Xf, Kf, biases, out);
    } else {
        fallback_conv<<<dim3(32768, 4), 256, 0, stream>>>(x, kern, biases, out);
    }
}